// Round 8
// baseline (723.465 us; speedup 1.0000x reference)
//
#include <hip/hip_runtime.h>

typedef __bf16 bf16;
typedef __bf16 bf16x4 __attribute__((ext_vector_type(4)));
typedef __bf16 bf16x8 __attribute__((ext_vector_type(8)));
typedef float f32x4 __attribute__((ext_vector_type(4)));

// ---------------------------------------------------------------------------
// GEMM: C[M,N] = A[M,K] * B[N,K]^T (+bias), MFMA bf16, fp32 accumulate.
// TA: float (convert fused into staging) or bf16. TC: float or bf16.
// B is always fp32 (weights), converted during staging.
// 128x128 tile, BK=64, 4 waves (2x2), 4x4 MFMA 16x16x32 per wave.
// Cross-validated vs naive VALU GEMM (rounds 4-7, bit-identical results).
// ---------------------------------------------------------------------------
template <typename TA, typename TC, bool ADD_BIAS>
__global__ __launch_bounds__(256) void gemm_bt(const TA* __restrict__ A,
                                               const float* __restrict__ B,
                                               const float* __restrict__ bias,
                                               TC* __restrict__ C,
                                               int M, int N, int K,
                                               int lda, int row0) {
  __shared__ __align__(16) bf16 As[128][72];
  __shared__ __align__(16) bf16 Bs[128][72];
  const int tid = threadIdx.x;
  const int lane = tid & 63;
  const int wid = tid >> 6;
  const int wr = wid >> 1, wc = wid & 1;
  const int m0 = blockIdx.y * 128;
  const int n0 = blockIdx.x * 128;
  const int l16 = lane & 15;
  const int lhi = lane >> 4;

  f32x4 acc[4][4] = {};

  for (int k0 = 0; k0 < K; k0 += 64) {
    __syncthreads();
#pragma unroll
    for (int p = 0; p < 8; ++p) {
      int v = tid + p * 256;   // 0..2047
      int row = v >> 4;        // 0..127
      int kc = (v & 15) * 4;   // 0..60
      size_t ai = (size_t)(row0 + m0 + row) * lda + k0 + kc;
      size_t bi = (size_t)(n0 + row) * K + k0 + kc;
      bf16x4 ab, bb;
      if constexpr (__is_same(TA, float)) {
        f32x4 a4 = *(const f32x4*)((const float*)A + ai);
#pragma unroll
        for (int j = 0; j < 4; ++j) ab[j] = (bf16)a4[j];
      } else {
        ab = *(const bf16x4*)((const bf16*)A + ai);
      }
      f32x4 b4 = *(const f32x4*)(B + bi);
#pragma unroll
      for (int j = 0; j < 4; ++j) bb[j] = (bf16)b4[j];
      *(bf16x4*)(&As[row][kc]) = ab;
      *(bf16x4*)(&Bs[row][kc]) = bb;
    }
    __syncthreads();
#pragma unroll
    for (int ks = 0; ks < 2; ++ks) {
      bf16x8 af[4], bfr[4];
#pragma unroll
      for (int i = 0; i < 4; ++i) {
        af[i] = *(const bf16x8*)(&As[wr * 64 + i * 16 + l16][ks * 32 + lhi * 8]);
        bfr[i] = *(const bf16x8*)(&Bs[wc * 64 + i * 16 + l16][ks * 32 + lhi * 8]);
      }
#pragma unroll
      for (int i = 0; i < 4; ++i)
#pragma unroll
        for (int j = 0; j < 4; ++j)
          acc[i][j] = __builtin_amdgcn_mfma_f32_16x16x32_bf16(af[i], bfr[j],
                                                              acc[i][j], 0, 0, 0);
    }
  }

  // C/D layout: col=lane&15, row=(lane>>4)*4+reg
#pragma unroll
  for (int i = 0; i < 4; ++i) {
    int row_base = m0 + wr * 64 + i * 16 + lhi * 4;
#pragma unroll
    for (int j = 0; j < 4; ++j) {
      int col = n0 + wc * 64 + j * 16 + l16;
      float bv = ADD_BIAS ? bias[col] : 0.0f;
#pragma unroll
      for (int r = 0; r < 4; ++r) {
        float val = acc[i][j][r] + bv;
        if constexpr (__is_same(TC, float))
          C[(size_t)(row_base + r) * N + col] = val;
        else
          C[(size_t)(row_base + r) * N + col] = (bf16)val;
      }
    }
  }
}

// ---------------------------------------------------------------------------
// MFMA flash attention, single batch, IN-PLACE into the q-columns of qkv.
// qkv [2048][3072] bf16 (q|k|v at cols 0|1024|2048). grid (32 q-tiles, 16
// heads), block 256 = 4 waves; wave w owns q rows [qtile*64+w*16, +16).
// Cross-validated vs simple VALU attention (rounds 3 vs 4, bf16-identical).
// Race-free in-place: block (qtile,h) is the only reader of the q-slice it
// overwrites (Q frags cached in regs first); K/V columns never written.
// ---------------------------------------------------------------------------
__global__ __launch_bounds__(256) void attn_fwd(bf16* __restrict__ qkv) {
  constexpr int S = 2048, D3 = 3072;
  __shared__ __align__(16) bf16 Vt[64][72];     // Vt[dim][key]
  __shared__ __align__(16) bf16 Pl[4][16][72];  // per-wave P[qrow][key]

  const int tid = threadIdx.x;
  const int lane = tid & 63;
  const int wid = tid >> 6;
  const int l16 = lane & 15, lhi = lane >> 4;
  const int h = blockIdx.y;
  const int q0 = blockIdx.x * 64 + wid * 16;

  bf16* qbase = qkv + h * 64;
  const bf16* kbase = qkv + 1024 + h * 64;
  const bf16* vbase = qkv + 2048 + h * 64;

  // Q fragments (A operand: m = lane&15, k = (lane>>4)*8 + j)
  bf16x8 qf[2];
#pragma unroll
  for (int ks = 0; ks < 2; ++ks)
    qf[ks] = *(const bf16x8*)(qbase + (size_t)(q0 + l16) * D3 + ks * 32 + lhi * 8);

  float mrow[4], lrow[4];
  f32x4 o[4] = {};
#pragma unroll
  for (int r = 0; r < 4; ++r) {
    mrow[r] = -1e30f;
    lrow[r] = 0.0f;
  }

  for (int t = 0; t < S; t += 64) {
    __syncthreads();
    // stage V transposed: thread handles key=tid&63, dim-octet tid>>6 (+4)
    {
      int key = tid & 63;
      int oc0 = tid >> 6;
#pragma unroll
      for (int p = 0; p < 2; ++p) {
        int oct = oc0 + p * 4;
        bf16x8 v = *(const bf16x8*)(vbase + (size_t)(t + key) * D3 + oct * 8);
#pragma unroll
        for (int j = 0; j < 8; ++j) Vt[oct * 8 + j][key] = v[j];
      }
    }
    __syncthreads();

    // QK^T: scores 16 x 64 per wave (4 col-tiles of 16 keys)
    f32x4 sc[4] = {};
#pragma unroll
    for (int ks = 0; ks < 2; ++ks) {
#pragma unroll
      for (int ct = 0; ct < 4; ++ct) {
        bf16x8 kf = *(const bf16x8*)(kbase + (size_t)(t + ct * 16 + l16) * D3 +
                                     ks * 32 + lhi * 8);
        sc[ct] = __builtin_amdgcn_mfma_f32_16x16x32_bf16(qf[ks], kf, sc[ct], 0, 0, 0);
      }
    }

    // online softmax; row r of this lane = lhi*4 + r, key col = l16 + 16*ct
#pragma unroll
    for (int r = 0; r < 4; ++r) {
      float mx = -1e30f;
#pragma unroll
      for (int ct = 0; ct < 4; ++ct) mx = fmaxf(mx, sc[ct][r]);
#pragma unroll
      for (int d = 1; d < 16; d <<= 1) mx = fmaxf(mx, __shfl_xor(mx, d));
      mx *= 0.125f;  // scale = 1/sqrt(64)
      float nm = fmaxf(mrow[r], mx);
      float alpha = __expf(mrow[r] - nm);
      mrow[r] = nm;
      float rs = 0.0f;
#pragma unroll
      for (int ct = 0; ct < 4; ++ct) {
        float p = __expf(sc[ct][r] * 0.125f - nm);
        sc[ct][r] = p;
        rs += p;
      }
#pragma unroll
      for (int d = 1; d < 16; d <<= 1) rs += __shfl_xor(rs, d);
      lrow[r] = lrow[r] * alpha + rs;
#pragma unroll
      for (int dt = 0; dt < 4; ++dt) o[dt][r] *= alpha;
    }

    // P: C-layout -> LDS (wave-private) -> A-layout frags
#pragma unroll
    for (int ct = 0; ct < 4; ++ct)
#pragma unroll
      for (int r = 0; r < 4; ++r)
        Pl[wid][lhi * 4 + r][ct * 16 + l16] = (bf16)sc[ct][r];
    __syncthreads();

    bf16x8 pf[2];
#pragma unroll
    for (int ks = 0; ks < 2; ++ks)
      pf[ks] = *(const bf16x8*)(&Pl[wid][l16][ks * 32 + lhi * 8]);

    // PV: out += P[16x64] * V[64x64]
#pragma unroll
    for (int ks = 0; ks < 2; ++ks) {
#pragma unroll
      for (int dt = 0; dt < 4; ++dt) {
        bf16x8 vf = *(const bf16x8*)(&Vt[dt * 16 + l16][ks * 32 + lhi * 8]);
        o[dt] = __builtin_amdgcn_mfma_f32_16x16x32_bf16(pf[ks], vf, o[dt], 0, 0, 0);
      }
    }
  }

  // epilogue: divide by l, write in-place into q columns
#pragma unroll
  for (int dt = 0; dt < 4; ++dt) {
#pragma unroll
    for (int r = 0; r < 4; ++r) {
      int row = q0 + lhi * 4 + r;
      qbase[(size_t)row * D3 + dt * 16 + l16] = (bf16)(o[dt][r] / lrow[r]);
    }
  }
}

// ---------------------------------------------------------------------------
extern "C" void kernel_launch(void* const* d_in, const int* in_sizes, int n_in,
                              void* d_out, int out_size, void* d_ws,
                              size_t ws_size, hipStream_t stream) {
  constexpr int B = 4, S = 2048, D = 1024;

  // Inputs resolved BY ELEMENT COUNT; fp32 confirmed (round-6 sniffer).
  const float* x = nullptr;
  const float* w_in = nullptr;
  const float* w_out = nullptr;
  const float* b_out = nullptr;
  for (int i = 0; i < n_in; ++i) {
    switch (in_sizes[i]) {
      case 8388608: x = (const float*)d_in[i]; break;
      case 3145728: w_in = (const float*)d_in[i]; break;
      case 1048576: w_out = (const float*)d_in[i]; break;
      case 1024: b_out = (const float*)d_in[i]; break;
    }
  }
  float* out = (float*)d_out;  // [4,2048,1024] FLOAT32 (reference output dtype)

  bf16* qkv = (bf16*)d_ws;  // [2048,3072] bf16 = 12 MiB per-batch scratch

  for (int b0 = 0; b0 < B; ++b0) {
    // QKV projection: x rows [b0*2048,+2048) (fp32) @ w_in^T -> qkv bf16
    gemm_bt<float, bf16, false><<<dim3(3 * D / 128, S / 128), 256, 0, stream>>>(
        x, w_in, nullptr, qkv, S, 3 * D, D, D, b0 * S);

    // MFMA flash attention, in-place into q-columns of qkv
    attn_fwd<<<dim3(S / 64, 16), 256, 0, stream>>>(qkv);

    // out projection + bias: qkv q-cols (bf16, lda=3072) @ w_out^T -> fp32
    gemm_bt<bf16, float, true><<<dim3(D / 128, S / 128), 256, 0, stream>>>(
        qkv, w_out, b_out, out + (size_t)b0 * S * D, S, D, D, 3 * D, 0);
  }
}

// Round 9
// 544.578 us; speedup vs baseline: 1.3285x; 1.3285x over previous
//
#include <hip/hip_runtime.h>

typedef __bf16 bf16;
typedef __bf16 bf16x4 __attribute__((ext_vector_type(4)));
typedef __bf16 bf16x8 __attribute__((ext_vector_type(8)));
typedef float f32x4 __attribute__((ext_vector_type(4)));

// ---------------------------------------------------------------------------
// GEMM: C[M,N] = A[M,K] * B[N,K]^T (+bias), MFMA bf16, fp32 accumulate.
// TA: float (convert fused into staging) or bf16. TC: float or bf16.
// 128x128 tile, BK=64, 4 waves (2x2), 4x4 MFMA 16x16x32 per wave.
// Cross-validated vs naive VALU GEMM (rounds 4-7, bit-identical results).
// ---------------------------------------------------------------------------
template <typename TA, typename TC, bool ADD_BIAS>
__global__ __launch_bounds__(256) void gemm_bt(const TA* __restrict__ A,
                                               const float* __restrict__ B,
                                               const float* __restrict__ bias,
                                               TC* __restrict__ C,
                                               int M, int N, int K,
                                               int lda, int row0) {
  __shared__ __align__(16) bf16 As[128][72];
  __shared__ __align__(16) bf16 Bs[128][72];
  const int tid = threadIdx.x;
  const int lane = tid & 63;
  const int wid = tid >> 6;
  const int wr = wid >> 1, wc = wid & 1;
  const int m0 = blockIdx.y * 128;
  const int n0 = blockIdx.x * 128;
  const int l16 = lane & 15;
  const int lhi = lane >> 4;

  f32x4 acc[4][4] = {};

  for (int k0 = 0; k0 < K; k0 += 64) {
    __syncthreads();
#pragma unroll
    for (int p = 0; p < 8; ++p) {
      int v = tid + p * 256;   // 0..2047
      int row = v >> 4;        // 0..127
      int kc = (v & 15) * 4;   // 0..60
      size_t ai = (size_t)(row0 + m0 + row) * lda + k0 + kc;
      size_t bi = (size_t)(n0 + row) * K + k0 + kc;
      bf16x4 ab, bb;
      if constexpr (__is_same(TA, float)) {
        f32x4 a4 = *(const f32x4*)((const float*)A + ai);
#pragma unroll
        for (int j = 0; j < 4; ++j) ab[j] = (bf16)a4[j];
      } else {
        ab = *(const bf16x4*)((const bf16*)A + ai);
      }
      f32x4 b4 = *(const f32x4*)(B + bi);
#pragma unroll
      for (int j = 0; j < 4; ++j) bb[j] = (bf16)b4[j];
      *(bf16x4*)(&As[row][kc]) = ab;
      *(bf16x4*)(&Bs[row][kc]) = bb;
    }
    __syncthreads();
#pragma unroll
    for (int ks = 0; ks < 2; ++ks) {
      bf16x8 af[4], bfr[4];
#pragma unroll
      for (int i = 0; i < 4; ++i) {
        af[i] = *(const bf16x8*)(&As[wr * 64 + i * 16 + l16][ks * 32 + lhi * 8]);
        bfr[i] = *(const bf16x8*)(&Bs[wc * 64 + i * 16 + l16][ks * 32 + lhi * 8]);
      }
#pragma unroll
      for (int i = 0; i < 4; ++i)
#pragma unroll
        for (int j = 0; j < 4; ++j)
          acc[i][j] = __builtin_amdgcn_mfma_f32_16x16x32_bf16(af[i], bfr[j],
                                                              acc[i][j], 0, 0, 0);
    }
  }

  // C/D layout: col=lane&15, row=(lane>>4)*4+reg
#pragma unroll
  for (int i = 0; i < 4; ++i) {
    int row_base = m0 + wr * 64 + i * 16 + lhi * 4;
#pragma unroll
    for (int j = 0; j < 4; ++j) {
      int col = n0 + wc * 64 + j * 16 + l16;
      float bv = ADD_BIAS ? bias[col] : 0.0f;
#pragma unroll
      for (int r = 0; r < 4; ++r) {
        float val = acc[i][j][r] + bv;
        if constexpr (__is_same(TC, float))
          C[(size_t)(row_base + r) * N + col] = val;
        else
          C[(size_t)(row_base + r) * N + col] = (bf16)val;
      }
    }
  }
}

// ---------------------------------------------------------------------------
// MFMA flash attention, IN-PLACE into q-columns of qkv [nb][2048][3072] bf16.
// grid (32 q-tiles, nb*16). Block 256 = 4 waves; wave w owns 16 q rows.
// Race-free: block (qtile,b,h) is sole reader of the q-slice it overwrites
// (Q frags cached in regs first); K/V columns never written.
// LDS 19 KB -> 8 blocks/CU; Pl stride 80 (lhi +8 banks, disjoint from l16's
// 0..7 -> conflict-free P writes); Pl barrier removed (wave-private, in-wave
// lgkmcnt ordering suffices).
// ---------------------------------------------------------------------------
__global__ __launch_bounds__(256) void attn_fwd(bf16* __restrict__ qkv) {
  constexpr int S = 2048, D3 = 3072;
  __shared__ __align__(16) bf16 Vt[64][72];     // Vt[dim][key], 9.2 KB
  __shared__ __align__(16) bf16 Pl[4][16][80];  // per-wave P[qrow][key], 10.2 KB

  const int tid = threadIdx.x;
  const int lane = tid & 63;
  const int wid = tid >> 6;
  const int l16 = lane & 15, lhi = lane >> 4;
  const int bh = blockIdx.y;
  const int b = bh >> 4, h = bh & 15;
  const int q0 = blockIdx.x * 64 + wid * 16;

  bf16* base = qkv + (size_t)b * S * D3;
  bf16* qbase = base + h * 64;
  const bf16* kbase = base + 1024 + h * 64;
  const bf16* vbase = base + 2048 + h * 64;

  // Q fragments (A operand: m = lane&15, k = (lane>>4)*8 + j)
  bf16x8 qf[2];
#pragma unroll
  for (int ks = 0; ks < 2; ++ks)
    qf[ks] = *(const bf16x8*)(qbase + (size_t)(q0 + l16) * D3 + ks * 32 + lhi * 8);

  float mrow[4], lrow[4];
  f32x4 o[4] = {};
#pragma unroll
  for (int r = 0; r < 4; ++r) {
    mrow[r] = -1e30f;
    lrow[r] = 0.0f;
  }

  for (int t = 0; t < S; t += 64) {
    __syncthreads();  // protect Vt vs previous iteration's PV reads
    {
      int key = tid & 63;
      int oc0 = tid >> 6;
#pragma unroll
      for (int p = 0; p < 2; ++p) {
        int oct = oc0 + p * 4;
        bf16x8 v = *(const bf16x8*)(vbase + (size_t)(t + key) * D3 + oct * 8);
#pragma unroll
        for (int j = 0; j < 8; ++j) Vt[oct * 8 + j][key] = v[j];
      }
    }
    __syncthreads();

    // QK^T: scores 16 x 64 per wave (4 col-tiles of 16 keys)
    f32x4 sc[4] = {};
#pragma unroll
    for (int ks = 0; ks < 2; ++ks) {
#pragma unroll
      for (int ct = 0; ct < 4; ++ct) {
        bf16x8 kf = *(const bf16x8*)(kbase + (size_t)(t + ct * 16 + l16) * D3 +
                                     ks * 32 + lhi * 8);
        sc[ct] = __builtin_amdgcn_mfma_f32_16x16x32_bf16(qf[ks], kf, sc[ct], 0, 0, 0);
      }
    }

    // online softmax; row r of this lane = lhi*4 + r
#pragma unroll
    for (int r = 0; r < 4; ++r) {
      float mx = -1e30f;
#pragma unroll
      for (int ct = 0; ct < 4; ++ct) mx = fmaxf(mx, sc[ct][r]);
#pragma unroll
      for (int d = 1; d < 16; d <<= 1) mx = fmaxf(mx, __shfl_xor(mx, d));
      mx *= 0.125f;  // 1/sqrt(64)
      float nm = fmaxf(mrow[r], mx);
      float alpha = __expf(mrow[r] - nm);
      mrow[r] = nm;
      float rs = 0.0f;
#pragma unroll
      for (int ct = 0; ct < 4; ++ct) {
        float p = __expf(sc[ct][r] * 0.125f - nm);
        sc[ct][r] = p;
        rs += p;
      }
#pragma unroll
      for (int d = 1; d < 16; d <<= 1) rs += __shfl_xor(rs, d);
      lrow[r] = lrow[r] * alpha + rs;
#pragma unroll
      for (int dt = 0; dt < 4; ++dt) o[dt][r] *= alpha;
    }

    // P: C-layout -> wave-private LDS -> A-layout frags (no barrier needed)
#pragma unroll
    for (int ct = 0; ct < 4; ++ct)
#pragma unroll
      for (int r = 0; r < 4; ++r)
        Pl[wid][lhi * 4 + r][ct * 16 + l16] = (bf16)sc[ct][r];

    bf16x8 pf[2];
#pragma unroll
    for (int ks = 0; ks < 2; ++ks)
      pf[ks] = *(const bf16x8*)(&Pl[wid][l16][ks * 32 + lhi * 8]);

    // PV: o += P[16x64] * V[64x64]
#pragma unroll
    for (int ks = 0; ks < 2; ++ks) {
#pragma unroll
      for (int dt = 0; dt < 4; ++dt) {
        bf16x8 vf = *(const bf16x8*)(&Vt[dt * 16 + l16][ks * 32 + lhi * 8]);
        o[dt] = __builtin_amdgcn_mfma_f32_16x16x32_bf16(pf[ks], vf, o[dt], 0, 0, 0);
      }
    }
  }

  // epilogue: divide by l, write in-place into q columns
#pragma unroll
  for (int dt = 0; dt < 4; ++dt) {
#pragma unroll
    for (int r = 0; r < 4; ++r) {
      int row = q0 + lhi * 4 + r;
      qbase[(size_t)row * D3 + dt * 16 + l16] = (bf16)(o[dt][r] / lrow[r]);
    }
  }
}

// ---------------------------------------------------------------------------
extern "C" void kernel_launch(void* const* d_in, const int* in_sizes, int n_in,
                              void* d_out, int out_size, void* d_ws,
                              size_t ws_size, hipStream_t stream) {
  constexpr int B = 4, S = 2048, D = 1024;

  const float* x = nullptr;
  const float* w_in = nullptr;
  const float* w_out = nullptr;
  const float* b_out = nullptr;
  for (int i = 0; i < n_in; ++i) {
    switch (in_sizes[i]) {
      case 8388608: x = (const float*)d_in[i]; break;
      case 3145728: w_in = (const float*)d_in[i]; break;
      case 1048576: w_out = (const float*)d_in[i]; break;
      case 1024: b_out = (const float*)d_in[i]; break;
    }
  }
  float* out = (float*)d_out;  // [4,2048,1024] fp32

  bf16* qkv = (bf16*)d_ws;
  const size_t need_full = (size_t)B * S * 3 * D * 2;  // 48 MiB

  if (ws_size >= need_full) {
    // Fully batched: 3 dispatches, max occupancy.
    gemm_bt<float, bf16, false><<<dim3(3 * D / 128, B * S / 128), 256, 0,
                                  stream>>>(x, w_in, nullptr, qkv, B * S,
                                            3 * D, D, D, 0);
    attn_fwd<<<dim3(S / 64, B * 16), 256, 0, stream>>>(qkv);
    gemm_bt<bf16, float, true><<<dim3(D / 128, B * S / 128), 256, 0, stream>>>(
        qkv, w_out, b_out, out, B * S, D, D, 3 * D, 0);
  } else {
    // Per-batch fallback (round-8 proven path), 12 MiB ws.
    for (int b0 = 0; b0 < B; ++b0) {
      gemm_bt<float, bf16, false><<<dim3(3 * D / 128, S / 128), 256, 0,
                                    stream>>>(x, w_in, nullptr, qkv, S, 3 * D,
                                              D, D, b0 * S);
      attn_fwd<<<dim3(S / 64, 16), 256, 0, stream>>>(qkv);
      gemm_bt<bf16, float, true><<<dim3(D / 128, S / 128), 256, 0, stream>>>(
          qkv, w_out, b_out, out + (size_t)b0 * S * D, S, D, D, 3 * D, 0);
    }
  }
}

// Round 10
// 517.115 us; speedup vs baseline: 1.3990x; 1.0531x over previous
//
#include <hip/hip_runtime.h>

typedef __bf16 bf16;
typedef __bf16 bf16x2 __attribute__((ext_vector_type(2)));
typedef __bf16 bf16x4 __attribute__((ext_vector_type(4)));
typedef __bf16 bf16x8 __attribute__((ext_vector_type(8)));
typedef float f32x4 __attribute__((ext_vector_type(4)));

// ---------------------------------------------------------------------------
// GEMM: C[M,N] = A[M,K] * B[N,K]^T (+bias), MFMA bf16, fp32 accumulate.
// (unchanged — proven rounds 8-9)
// ---------------------------------------------------------------------------
template <typename TA, typename TC, bool ADD_BIAS>
__global__ __launch_bounds__(256) void gemm_bt(const TA* __restrict__ A,
                                               const float* __restrict__ B,
                                               const float* __restrict__ bias,
                                               TC* __restrict__ C,
                                               int M, int N, int K,
                                               int lda, int row0) {
  __shared__ __align__(16) bf16 As[128][72];
  __shared__ __align__(16) bf16 Bs[128][72];
  const int tid = threadIdx.x;
  const int lane = tid & 63;
  const int wid = tid >> 6;
  const int wr = wid >> 1, wc = wid & 1;
  const int m0 = blockIdx.y * 128;
  const int n0 = blockIdx.x * 128;
  const int l16 = lane & 15;
  const int lhi = lane >> 4;

  f32x4 acc[4][4] = {};

  for (int k0 = 0; k0 < K; k0 += 64) {
    __syncthreads();
#pragma unroll
    for (int p = 0; p < 8; ++p) {
      int v = tid + p * 256;
      int row = v >> 4;
      int kc = (v & 15) * 4;
      size_t ai = (size_t)(row0 + m0 + row) * lda + k0 + kc;
      size_t bi = (size_t)(n0 + row) * K + k0 + kc;
      bf16x4 ab, bb;
      if constexpr (__is_same(TA, float)) {
        f32x4 a4 = *(const f32x4*)((const float*)A + ai);
#pragma unroll
        for (int j = 0; j < 4; ++j) ab[j] = (bf16)a4[j];
      } else {
        ab = *(const bf16x4*)((const bf16*)A + ai);
      }
      f32x4 b4 = *(const f32x4*)(B + bi);
#pragma unroll
      for (int j = 0; j < 4; ++j) bb[j] = (bf16)b4[j];
      *(bf16x4*)(&As[row][kc]) = ab;
      *(bf16x4*)(&Bs[row][kc]) = bb;
    }
    __syncthreads();
#pragma unroll
    for (int ks = 0; ks < 2; ++ks) {
      bf16x8 af[4], bfr[4];
#pragma unroll
      for (int i = 0; i < 4; ++i) {
        af[i] = *(const bf16x8*)(&As[wr * 64 + i * 16 + l16][ks * 32 + lhi * 8]);
        bfr[i] = *(const bf16x8*)(&Bs[wc * 64 + i * 16 + l16][ks * 32 + lhi * 8]);
      }
#pragma unroll
      for (int i = 0; i < 4; ++i)
#pragma unroll
        for (int j = 0; j < 4; ++j)
          acc[i][j] = __builtin_amdgcn_mfma_f32_16x16x32_bf16(af[i], bfr[j],
                                                              acc[i][j], 0, 0, 0);
    }
  }

#pragma unroll
  for (int i = 0; i < 4; ++i) {
    int row_base = m0 + wr * 64 + i * 16 + lhi * 4;
#pragma unroll
    for (int j = 0; j < 4; ++j) {
      int col = n0 + wc * 64 + j * 16 + l16;
      float bv = ADD_BIAS ? bias[col] : 0.0f;
#pragma unroll
      for (int r = 0; r < 4; ++r) {
        float val = acc[i][j][r] + bv;
        if constexpr (__is_same(TC, float))
          C[(size_t)(row_base + r) * N + col] = val;
        else
          C[(size_t)(row_base + r) * N + col] = (bf16)val;
      }
    }
  }
}

// ---------------------------------------------------------------------------
// MFMA flash attention v2: K·Q^T orientation -> per-lane scalar softmax state.
// IN-PLACE into q-columns of qkv [nb][2048][3072] bf16. grid (32, nb*16),
// 4 waves/block, wave owns 16 q rows; lane's q-row = l16, per K-tile lane
// holds 16 keys (4 ct-tiles x 4 regs). P staged via 4x ds_write_b64 into
// wave-private LDS; PV is A=V^T (Vt reads), B=P. Strides 80 bf16 (160 B,
// 16B-aligned for b128; Vt writes bank=8j+kp -> conflict-free).
// ---------------------------------------------------------------------------
__global__ __launch_bounds__(256) void attn_fwd(bf16* __restrict__ qkv) {
  constexpr int S = 2048, D3 = 3072;
  __shared__ __align__(16) bf16 Vt[64][80];     // [dim][key] 10 KB
  __shared__ __align__(16) bf16 Pq[4][16][80];  // per-wave [qrow][key] 10 KB

  const int tid = threadIdx.x;
  const int lane = tid & 63;
  const int wid = tid >> 6;
  const int l16 = lane & 15, lhi = lane >> 4;
  const int bh = blockIdx.y;
  const int b = bh >> 4, h = bh & 15;
  const int q0 = blockIdx.x * 64 + wid * 16;

  bf16* base = qkv + (size_t)b * S * D3;
  bf16* qbase = base + h * 64;
  const bf16* kbase = base + 1024 + h * 64;
  const bf16* vbase = base + 2048 + h * 64;

  // Q fragments, B-operand: n(qrow)=l16, k=lhi*8+j  (cached before overwrite)
  bf16x8 qf[2];
#pragma unroll
  for (int ks = 0; ks < 2; ++ks)
    qf[ks] = *(const bf16x8*)(qbase + (size_t)(q0 + l16) * D3 + ks * 32 + lhi * 8);

  float m_i = -1e30f, l_i = 0.0f;  // per-lane: q-row = q0 + l16
  f32x4 o[4] = {};

  for (int t = 0; t < S; t += 64) {
    __syncthreads();  // Vt: protect vs previous iteration's PV reads
    // V stage: thread handles key-pair kp=tid&31 (keys 2kp,2kp+1), octet tid>>5
    {
      int kp = tid & 31, oc = tid >> 5;
      bf16x8 v0 = *(const bf16x8*)(vbase + (size_t)(t + 2 * kp) * D3 + oc * 8);
      bf16x8 v1 = *(const bf16x8*)(vbase + (size_t)(t + 2 * kp + 1) * D3 + oc * 8);
#pragma unroll
      for (int j = 0; j < 8; ++j) {
        bf16x2 pr;
        pr[0] = v0[j];
        pr[1] = v1[j];
        *(bf16x2*)(&Vt[oc * 8 + j][2 * kp]) = pr;
      }
    }
    __syncthreads();

    // K·Q^T: sc[ct][r] = score(key = t + ct*16 + lhi*4 + r, qrow = l16)
    f32x4 sc[4] = {};
#pragma unroll
    for (int ct = 0; ct < 4; ++ct) {
#pragma unroll
      for (int ks = 0; ks < 2; ++ks) {
        bf16x8 kf = *(const bf16x8*)(kbase + (size_t)(t + ct * 16 + l16) * D3 +
                                     ks * 32 + lhi * 8);
        sc[ct] = __builtin_amdgcn_mfma_f32_16x16x32_bf16(kf, qf[ks], sc[ct], 0, 0, 0);
      }
    }

    // online softmax, scalar state per lane (one q-row)
    float mx = sc[0][0];
#pragma unroll
    for (int ct = 0; ct < 4; ++ct)
#pragma unroll
      for (int r = 0; r < 4; ++r) mx = fmaxf(mx, sc[ct][r]);
    mx = fmaxf(mx, __shfl_xor(mx, 16));
    mx = fmaxf(mx, __shfl_xor(mx, 32));
    mx *= 0.125f;  // 1/sqrt(64)
    float nm = fmaxf(m_i, mx);
    float alpha = __expf(m_i - nm);
    m_i = nm;
    float rs = 0.0f;
#pragma unroll
    for (int ct = 0; ct < 4; ++ct)
#pragma unroll
      for (int r = 0; r < 4; ++r) {
        float p = __expf(sc[ct][r] * 0.125f - nm);
        sc[ct][r] = p;
        rs += p;
      }
    rs += __shfl_xor(rs, 16);
    rs += __shfl_xor(rs, 32);
    l_i = l_i * alpha + rs;
#pragma unroll
    for (int dt = 0; dt < 4; ++dt)
#pragma unroll
      for (int r = 0; r < 4; ++r) o[dt][r] *= alpha;

    // P stage: Pq[qrow][key] = P[key][qrow]; 4x packed ds_write_b64
#pragma unroll
    for (int ct = 0; ct < 4; ++ct) {
      bf16x4 pk;
#pragma unroll
      for (int r = 0; r < 4; ++r) pk[r] = (bf16)sc[ct][r];
      *(bf16x4*)(&Pq[wid][l16][ct * 16 + lhi * 4]) = pk;
    }
    // B-operand frags (wave-private RAW, compiler lgkmcnt suffices)
    bf16x8 pf0 = *(const bf16x8*)(&Pq[wid][l16][lhi * 8]);
    bf16x8 pf1 = *(const bf16x8*)(&Pq[wid][l16][32 + lhi * 8]);

    // PV: o[m=dh][n=qrow] += V^T x P ; A-frag from Vt
#pragma unroll
    for (int dt = 0; dt < 4; ++dt) {
      bf16x8 vf0 = *(const bf16x8*)(&Vt[dt * 16 + l16][lhi * 8]);
      bf16x8 vf1 = *(const bf16x8*)(&Vt[dt * 16 + l16][32 + lhi * 8]);
      o[dt] = __builtin_amdgcn_mfma_f32_16x16x32_bf16(vf0, pf0, o[dt], 0, 0, 0);
      o[dt] = __builtin_amdgcn_mfma_f32_16x16x32_bf16(vf1, pf1, o[dt], 0, 0, 0);
    }
  }

  // epilogue: O[qrow=l16][dh=dt*16+lhi*4+r]/l -> transpose via Pq -> 16B stores
  float rl = 1.0f / l_i;
#pragma unroll
  for (int dt = 0; dt < 4; ++dt) {
    bf16x4 ok;
#pragma unroll
    for (int r = 0; r < 4; ++r) ok[r] = (bf16)(o[dt][r] * rl);
    *(bf16x4*)(&Pq[wid][l16][dt * 16 + lhi * 4]) = ok;
  }
  bf16x8 r0 = *(const bf16x8*)(&Pq[wid][l16][lhi * 16]);
  bf16x8 r1 = *(const bf16x8*)(&Pq[wid][l16][lhi * 16 + 8]);
  bf16* orow = qbase + (size_t)(q0 + l16) * D3 + lhi * 16;
  *(bf16x8*)(orow) = r0;
  *(bf16x8*)(orow + 8) = r1;
}

// ---------------------------------------------------------------------------
extern "C" void kernel_launch(void* const* d_in, const int* in_sizes, int n_in,
                              void* d_out, int out_size, void* d_ws,
                              size_t ws_size, hipStream_t stream) {
  constexpr int B = 4, S = 2048, D = 1024;

  const float* x = nullptr;
  const float* w_in = nullptr;
  const float* w_out = nullptr;
  const float* b_out = nullptr;
  for (int i = 0; i < n_in; ++i) {
    switch (in_sizes[i]) {
      case 8388608: x = (const float*)d_in[i]; break;
      case 3145728: w_in = (const float*)d_in[i]; break;
      case 1048576: w_out = (const float*)d_in[i]; break;
      case 1024: b_out = (const float*)d_in[i]; break;
    }
  }
  float* out = (float*)d_out;  // [4,2048,1024] fp32

  bf16* qkv = (bf16*)d_ws;
  const size_t need_full = (size_t)B * S * 3 * D * 2;  // 48 MiB

  if (ws_size >= need_full) {
    gemm_bt<float, bf16, false><<<dim3(3 * D / 128, B * S / 128), 256, 0,
                                  stream>>>(x, w_in, nullptr, qkv, B * S,
                                            3 * D, D, D, 0);
    attn_fwd<<<dim3(S / 64, B * 16), 256, 0, stream>>>(qkv);
    gemm_bt<bf16, float, true><<<dim3(D / 128, B * S / 128), 256, 0, stream>>>(
        qkv, w_out, b_out, out, B * S, D, D, 3 * D, 0);
  } else {
    for (int b0 = 0; b0 < B; ++b0) {
      gemm_bt<float, bf16, false><<<dim3(3 * D / 128, S / 128), 256, 0,
                                    stream>>>(x, w_in, nullptr, qkv, S, 3 * D,
                                              D, D, b0 * S);
      attn_fwd<<<dim3(S / 64, 16), 256, 0, stream>>>(qkv);
      gemm_bt<bf16, float, true><<<dim3(D / 128, S / 128), 256, 0, stream>>>(
          qkv, w_out, b_out, out + (size_t)b0 * S * D, S, D, D, 3 * D, 0);
    }
  }
}